// Round 1
// baseline (6595.060 us; speedup 1.0000x reference)
//
#include <hip/hip_runtime.h>
#include <stdint.h>

typedef __attribute__((ext_vector_type(8))) short short8;
typedef __attribute__((ext_vector_type(4))) float f32x4;

__device__ inline unsigned short f2bf(float f) {
  union { float f; uint32_t u; } v; v.f = f;
  uint32_t u = v.u;
  u += 0x7FFFu + ((u >> 16) & 1u);
  return (unsigned short)(u >> 16);
}

__device__ inline short8 pack8(float4 a, float4 b) {
  short8 r;
  r[0] = (short)f2bf(a.x); r[1] = (short)f2bf(a.y);
  r[2] = (short)f2bf(a.z); r[3] = (short)f2bf(a.w);
  r[4] = (short)f2bf(b.x); r[5] = (short)f2bf(b.y);
  r[6] = (short)f2bf(b.z); r[7] = (short)f2bf(b.w);
  return r;
}

__device__ inline float dot4(float4 a, float4 b) {
  return a.x * b.x + a.y * b.y + a.z * b.z + a.w * b.w;
}

// Manual grid barrier: grid <= 256 blocks (1/CU max) => co-residency guaranteed.
__device__ inline void grid_barrier(int* cnt, int* gen, int nblk) {
  __syncthreads();
  if (threadIdx.x == 0) {
    __threadfence();
    int g = __hip_atomic_load(gen, __ATOMIC_RELAXED, __HIP_MEMORY_SCOPE_AGENT);
    int prev = __hip_atomic_fetch_add(cnt, 1, __ATOMIC_ACQ_REL, __HIP_MEMORY_SCOPE_AGENT);
    if (prev == nblk - 1) {
      __hip_atomic_store(cnt, 0, __ATOMIC_RELAXED, __HIP_MEMORY_SCOPE_AGENT);
      __hip_atomic_fetch_add(gen, 1, __ATOMIC_RELEASE, __HIP_MEMORY_SCOPE_AGENT);
    } else {
      while (__hip_atomic_load(gen, __ATOMIC_ACQUIRE, __HIP_MEMORY_SCOPE_AGENT) == g) {
        __builtin_amdgcn_s_sleep(2);
      }
    }
    __threadfence();
  }
  __syncthreads();
}

// Gather + bf16-convert embeddings. rows 0..2047: xbf (src, row = s*32+b).
// rows 2048..3583: ebf (trg teacher-forcing, row = t*32+b), also writes e-cols of Z.
__global__ __launch_bounds__(128) void prep_gather(
    const int* __restrict__ src, const int* __restrict__ trg,
    const float* __restrict__ emb,
    unsigned short* __restrict__ xbf, unsigned short* __restrict__ ebf,
    unsigned short* __restrict__ Zbf) {
  int r = blockIdx.x, tid = threadIdx.x;
  if (r < 2048) {
    int b = r & 31, s = r >> 5;
    int tok = src[b * 64 + s];
    const float* e = emb + (size_t)tok * 512;
    float4 v = *(const float4*)(e + tid * 4);
    unsigned short* dst = xbf + (size_t)r * 512 + tid * 4;
    dst[0] = f2bf(v.x); dst[1] = f2bf(v.y); dst[2] = f2bf(v.z); dst[3] = f2bf(v.w);
  } else {
    int rr = r - 2048;
    int t = rr >> 5, b = rr & 31;
    unsigned short* dst = ebf + (size_t)rr * 512 + tid * 4;
    if (t < 47) {
      int tok = trg[t * 32 + b];
      const float* e = emb + (size_t)tok * 512;
      float4 v = *(const float4*)(e + tid * 4);
      unsigned short q0 = f2bf(v.x), q1 = f2bf(v.y), q2 = f2bf(v.z), q3 = f2bf(v.w);
      dst[0] = q0; dst[1] = q1; dst[2] = q2; dst[3] = q3;
      unsigned short* zd = Zbf + (size_t)rr * 2048 + 1536 + tid * 4;
      zd[0] = q0; zd[1] = q1; zd[2] = q2; zd[3] = q3;
    } else {
      dst[0] = 0; dst[1] = 0; dst[2] = 0; dst[3] = 0;
    }
  }
}

// C[m,n] = sum_k A[m,k]*B[n,k] (+bias[n]). A bf16 (ABF) or f32; B f32 converted inline.
// 128x128 tile, BK=32, 4 waves each 64x64 via 4x4 16x16x32 bf16 MFMA fragments.
template <bool ABF>
__global__ __launch_bounds__(256) void gemm_kernel(
    const void* __restrict__ Av, int lda,
    const float* __restrict__ Bsrc, int ldb, int bco,
    const float* __restrict__ bias,
    float* __restrict__ C, int ldc,
    int K, int Mvalid, int row_off) {
  __shared__ __align__(16) unsigned short As[128 * 32];
  __shared__ __align__(16) unsigned short Bs[128 * 32];
  const int tid = threadIdx.x;
  const int m0 = blockIdx.x * 128, n0 = blockIdx.y * 128;
  const int w = tid >> 6, lane = tid & 63;
  const int wm = w >> 1, wn = w & 1;
  const int fr = lane & 15, fq = lane >> 4;
  f32x4 acc[4][4];
#pragma unroll
  for (int mi = 0; mi < 4; ++mi) {
#pragma unroll
    for (int ni = 0; ni < 4; ++ni) acc[mi][ni] = (f32x4){0.f, 0.f, 0.f, 0.f};
  }
  for (int k0 = 0; k0 < K; k0 += 32) {
#pragma unroll
    for (int p = 0; p < 2; ++p) {
      int idx = p * 256 + tid;
      int row = idx >> 2, seg = idx & 3;
      if (ABF) {
        const unsigned short* Ab = (const unsigned short*)Av;
        *(short8*)(As + row * 32 + seg * 8) =
            *(const short8*)(Ab + (size_t)(m0 + row) * lda + k0 + seg * 8);
      } else {
        const float* Af = (const float*)Av;
        const float* ap = Af + (size_t)(m0 + row) * lda + k0 + seg * 8;
        *(short8*)(As + row * 32 + seg * 8) = pack8(*(const float4*)ap, *(const float4*)(ap + 4));
      }
      const float* bp = Bsrc + (size_t)(n0 + row) * ldb + bco + k0 + seg * 8;
      *(short8*)(Bs + row * 32 + seg * 8) = pack8(*(const float4*)bp, *(const float4*)(bp + 4));
    }
    __syncthreads();
    short8 af[4], bf[4];
#pragma unroll
    for (int mi = 0; mi < 4; ++mi)
      af[mi] = *(const short8*)(As + (wm * 64 + mi * 16 + fr) * 32 + fq * 8);
#pragma unroll
    for (int ni = 0; ni < 4; ++ni)
      bf[ni] = *(const short8*)(Bs + (wn * 64 + ni * 16 + fr) * 32 + fq * 8);
#pragma unroll
    for (int mi = 0; mi < 4; ++mi) {
#pragma unroll
      for (int ni = 0; ni < 4; ++ni)
        acc[mi][ni] = __builtin_amdgcn_mfma_f32_16x16x32_bf16(af[mi], bf[ni], acc[mi][ni], 0, 0, 0);
    }
    __syncthreads();
  }
#pragma unroll
  for (int mi = 0; mi < 4; ++mi) {
#pragma unroll
    for (int ni = 0; ni < 4; ++ni) {
      int col = n0 + wn * 64 + ni * 16 + fr;
      float bv = bias ? bias[col] : 0.f;
#pragma unroll
      for (int j = 0; j < 4; ++j) {
        int rowm = m0 + wm * 64 + mi * 16 + fq * 4 + j;
        if (rowm < Mvalid) C[(size_t)(rowm + row_off) * ldc + col] = acc[mi][ni][j] + bv;
      }
    }
  }
}

// Bidirectional GRU encoder recurrence. 128 blocks: blk>>6 = dir, (blk&63)*8 = d-slice.
// 1 grid barrier per step. Whh slice staged once in LDS; h staged per step.
__global__ __launch_bounds__(256) void enc_kernel(
    const float* __restrict__ Gif, const float* __restrict__ Gib,
    const float* __restrict__ whF, const float* __restrict__ whB,
    const float* __restrict__ bhhF, const float* __restrict__ bhhB,
    const float* __restrict__ fcW, const float* __restrict__ fcb,
    float* __restrict__ hbuf, float* __restrict__ enc_out,
    float* __restrict__ s0buf, int* __restrict__ bar) {
  const int blk = blockIdx.x, tid = threadIdx.x;
  const int dir = blk >> 6, jb = blk & 63, D0 = jb * 8;
  const float* Whh = dir ? whB : whF;
  const float* Gi = dir ? Gib : Gif;
  const float* bhh = dir ? bhhB : bhhF;
  __shared__ __align__(16) float wlds[24 * 516];
  __shared__ __align__(16) float hlds[32 * 516];
  for (int idx = tid; idx < 24 * 512; idx += 256) {
    int lr = idx >> 9, k = idx & 511;
    int gr = (lr >> 3) * 512 + D0 + (lr & 7);
    wlds[lr * 516 + k] = Whh[(size_t)gr * 512 + k];
  }
  const int b = tid >> 3, i = tid & 7;
  float* hb = hbuf + (size_t)dir * (2 * 32 * 512);
  for (int t = 0; t < 64; ++t) {
    const int cur = t & 1;
    const float* hsrc = hb + cur * (32 * 512);
#pragma unroll
    for (int q = 0; q < 16; ++q) {
      int f = q * 1024 + tid * 4;
      int bb = f >> 9, kk = f & 511;
      *(float4*)(hlds + bb * 516 + kk) = *(const float4*)(hsrc + f);
    }
    __syncthreads();
    float ar = 0.f, az = 0.f, an = 0.f;
    const float* wr0 = wlds + i * 516;
    const float* wr1 = wlds + (8 + i) * 516;
    const float* wr2 = wlds + (16 + i) * 516;
    const float* hrow = hlds + b * 516;
#pragma unroll 4
    for (int kq = 0; kq < 512; kq += 4) {
      float4 hv = *(const float4*)(hrow + kq);
      ar += dot4(hv, *(const float4*)(wr0 + kq));
      az += dot4(hv, *(const float4*)(wr1 + kq));
      an += dot4(hv, *(const float4*)(wr2 + kq));
    }
    const int d = D0 + i;
    const int srow = dir ? (63 - t) : t;
    const float* gi = Gi + ((size_t)srow * 32 + b) * 1536;
    float rg = gi[d] + ar + bhh[d];
    float zg = gi[512 + d] + az + bhh[512 + d];
    float hn = an + bhh[1024 + d];
    float r = 1.f / (1.f + __expf(-rg));
    float z = 1.f / (1.f + __expf(-zg));
    float n = tanhf(gi[1024 + d] + r * hn);
    float h2 = (1.f - z) * n + z * hrow[d];
    hb[(1 - cur) * (32 * 512) + b * 512 + d] = h2;
    enc_out[((size_t)b * 64 + srow) * 1024 + (dir ? 512 + d : d)] = h2;
    grid_barrier(bar, bar + 1, 128);
  }
  // s0 = tanh([hf,hb] @ fc_W^T + fc_b). Final h is in phase-0 buffers.
  if (tid < 128) {
    const int bb = tid >> 2, d = blk * 4 + (tid & 3);
    const float* hf = hbuf + (size_t)bb * 512;
    const float* hbk = hbuf + (size_t)(2 * 32 * 512) + bb * 512;
    float acc = fcb[d];
    for (int k = 0; k < 512; k += 4) {
      acc += dot4(*(const float4*)(hf + k), *(const float4*)(fcW + (size_t)d * 1024 + k));
      acc += dot4(*(const float4*)(hbk + k), *(const float4*)(fcW + (size_t)d * 1024 + 512 + k));
    }
    s0buf[bb * 512 + d] = tanhf(acc);
  }
}

// Attention decoder recurrence. 128 blocks, 3 grid barriers per step.
// P1: sproj (d-sliced, all b) + gh = s@Whh^T (+bhh). P2: scores. P3: softmax+c+gic+gates.
__global__ __launch_bounds__(256) void dec_kernel(
    const float* __restrict__ attnW, const float* __restrict__ attnV,
    const float* __restrict__ decWhh, const float* __restrict__ decBhh,
    const float* __restrict__ encproj, const float* __restrict__ EP2,
    const float* __restrict__ Gie, const float* __restrict__ enc_out,
    float* __restrict__ sbufs, float* __restrict__ sprojb,
    float* __restrict__ ghbuf, float* __restrict__ scoresb,
    unsigned short* __restrict__ Zbf, int* __restrict__ bar) {
  const int blk = blockIdx.x, tid = threadIdx.x;
  __shared__ __align__(16) float slds[32 * 516];
  __shared__ __align__(16) float plds[512];
  __shared__ float raw[64];
  __shared__ float aa[64];
  __shared__ float gic_lds[384];
  const int d4 = blk * 4;
  const int bq = blk >> 2, qq = blk & 3;
  for (int t = 0; t < 47; ++t) {
    const float* scur = sbufs + (t & 1) * (32 * 512);
    float* snext = sbufs + ((t + 1) & 1) * (32 * 512);
#pragma unroll
    for (int q = 0; q < 16; ++q) {
      int f = q * 1024 + tid * 4;
      int bb = f >> 9, kk = f & 511;
      *(float4*)(slds + bb * 516 + kk) = *(const float4*)(scur + f);
    }
    __syncthreads();
    // P1
#pragma unroll
    for (int rep = 0; rep < 2; ++rep) {
      int oi = rep * 256 + tid;
      if (oi < 128) {
        int bb = oi >> 2, dd = oi & 3;
        const float* wrow = attnW + (size_t)(d4 + dd) * 1536;
        const float* srow = slds + bb * 516;
        float acc2 = 0.f;
        for (int kq = 0; kq < 512; kq += 4)
          acc2 += dot4(*(const float4*)(srow + kq), *(const float4*)(wrow + kq));
        sprojb[bb * 512 + d4 + dd] = acc2;
      } else {
        int gidx = oi - 128;
        int bb = gidx / 12, rr = gidx - bb * 12;
        int rowg = (rr >> 2) * 512 + d4 + (rr & 3);
        const float* wrow = decWhh + (size_t)rowg * 512;
        const float* srow = slds + bb * 516;
        float acc2 = decBhh[rowg];
        for (int kq = 0; kq < 512; kq += 4)
          acc2 += dot4(*(const float4*)(srow + kq), *(const float4*)(wrow + kq));
        ghbuf[bb * 1536 + rowg] = acc2;
      }
    }
    grid_barrier(bar, bar + 1, 128);
    // P2: scores[bq][qq*16..+15]
    if (tid < 128)
      *(float4*)(plds + tid * 4) = *(const float4*)(sprojb + bq * 512 + tid * 4);
    __syncthreads();
    {
      int si = qq * 16 + (tid >> 4), l16 = tid & 15;
      const float* ep = encproj + ((size_t)bq * 64 + si) * 512 + l16 * 32;
      const float* pp = plds + l16 * 32;
      const float* vv = attnV + l16 * 32;
      float part = 0.f;
#pragma unroll 4
      for (int j = 0; j < 32; ++j) part += tanhf(pp[j] + ep[j]) * vv[j];
      part += __shfl_xor(part, 1, 16);
      part += __shfl_xor(part, 2, 16);
      part += __shfl_xor(part, 4, 16);
      part += __shfl_xor(part, 8, 16);
      if (l16 == 0) scoresb[bq * 64 + si] = part;
    }
    grid_barrier(bar, bar + 1, 128);
    // P3: softmax (redundant per block), c-slice, gic via EP2, gates
    if (tid < 64) raw[tid] = scoresb[bq * 64 + tid];
    __syncthreads();
    float mx = raw[0];
#pragma unroll
    for (int s2 = 1; s2 < 64; ++s2) mx = fmaxf(mx, raw[s2]);
    float den = 0.f;
#pragma unroll
    for (int s2 = 0; s2 < 64; ++s2) den += __expf(raw[s2] - mx);
    if (tid < 64) aa[tid] = __expf(raw[tid] - mx) / den;
    __syncthreads();
    {
      int j = qq * 256 + tid;
      float cc = 0.f;
      const float* eo = enc_out + (size_t)bq * 64 * 1024 + j;
#pragma unroll 8
      for (int s2 = 0; s2 < 64; ++s2) cc += aa[s2] * eo[(size_t)s2 * 1024];
      Zbf[((size_t)t * 32 + bq) * 2048 + 512 + j] = f2bf(cc);
    }
#pragma unroll
    for (int rep = 0; rep < 2; ++rep) {
      int oi = rep * 256 + tid;
      if (oi < 384) {
        int g = oi >> 7, dd = oi & 127;
        int rowg = g * 512 + qq * 128 + dd;
        const float* e2 = EP2 + (size_t)bq * 64 * 1536 + rowg;
        float acc2 = 0.f;
#pragma unroll 8
        for (int s2 = 0; s2 < 64; ++s2) acc2 += aa[s2] * e2[(size_t)s2 * 1536];
        gic_lds[oi] = acc2;
      }
    }
    __syncthreads();
    if (tid < 128) {
      int d = qq * 128 + tid;
      const float* gie = Gie + ((size_t)t * 32 + bq) * 1536;
      float grv = gie[d] + gic_lds[tid] + ghbuf[bq * 1536 + d];
      float gzv = gie[512 + d] + gic_lds[128 + tid] + ghbuf[bq * 1536 + 512 + d];
      float ginv = gie[1024 + d] + gic_lds[256 + tid];
      float ghnv = ghbuf[bq * 1536 + 1024 + d];
      float r = 1.f / (1.f + __expf(-grv));
      float z = 1.f / (1.f + __expf(-gzv));
      float n = tanhf(ginv + r * ghnv);
      float s2v = (1.f - z) * n + z * slds[bq * 516 + d];
      snext[bq * 512 + d] = s2v;
      Zbf[((size_t)t * 32 + bq) * 2048 + d] = f2bf(s2v);
    }
    grid_barrier(bar, bar + 1, 128);
  }
}

extern "C" void kernel_launch(void* const* d_in, const int* in_sizes, int n_in,
                              void* d_out, int out_size, void* d_ws, size_t ws_size,
                              hipStream_t stream) {
  (void)in_sizes; (void)n_in; (void)out_size; (void)ws_size;
  const int* src = (const int*)d_in[0];
  const int* trg = (const int*)d_in[1];
  const float* emb = (const float*)d_in[2];
  const float* encf_Wih = (const float*)d_in[3];
  const float* encf_Whh = (const float*)d_in[4];
  const float* encf_bih = (const float*)d_in[5];
  const float* encf_bhh = (const float*)d_in[6];
  const float* encb_Wih = (const float*)d_in[7];
  const float* encb_Whh = (const float*)d_in[8];
  const float* encb_bih = (const float*)d_in[9];
  const float* encb_bhh = (const float*)d_in[10];
  const float* fc_W = (const float*)d_in[11];
  const float* fc_b = (const float*)d_in[12];
  const float* attn_W = (const float*)d_in[13];
  const float* attn_v = (const float*)d_in[14];
  const float* dec_Wih = (const float*)d_in[15];
  const float* dec_Whh = (const float*)d_in[16];
  const float* dec_bih = (const float*)d_in[17];
  const float* dec_bhh = (const float*)d_in[18];
  const float* out_W = (const float*)d_in[19];
  const float* out_b = (const float*)d_in[20];
  float* out = (float*)d_out;

  char* p = (char*)d_ws;
  size_t off = 0;
  auto alloc = [&](size_t bytes) {
    void* r = p + off;
    off = (off + bytes + 255) & ~(size_t)255;
    return r;
  };
  int* bar = (int*)alloc(256);
  unsigned short* xbf = (unsigned short*)alloc((size_t)2048 * 512 * 2);
  unsigned short* ebf = (unsigned short*)alloc((size_t)1536 * 512 * 2);
  unsigned short* Zbf = (unsigned short*)alloc((size_t)1536 * 2048 * 2);
  float* Gif = (float*)alloc((size_t)2048 * 1536 * 4);
  float* Gib = (float*)alloc((size_t)2048 * 1536 * 4);
  float* Gie = (float*)alloc((size_t)1536 * 1536 * 4);
  float* enc_out = (float*)alloc((size_t)2048 * 1024 * 4);
  float* encproj = (float*)alloc((size_t)2048 * 512 * 4);
  float* EP2 = (float*)alloc((size_t)2048 * 1536 * 4);
  float* hbuf = (float*)alloc((size_t)2 * 2 * 32 * 512 * 4);
  float* sbufs = (float*)alloc((size_t)2 * 32 * 512 * 4);
  float* sprojb = (float*)alloc((size_t)32 * 512 * 4);
  float* ghbuf = (float*)alloc((size_t)32 * 1536 * 4);
  float* scoresb = (float*)alloc((size_t)32 * 64 * 4);

  hipMemsetAsync(bar, 0, 256, stream);
  hipMemsetAsync(Zbf, 0, (size_t)1536 * 2048 * 2, stream);
  hipMemsetAsync(hbuf, 0, (size_t)2 * 2 * 32 * 512 * 4, stream);
  hipMemsetAsync(d_out, 0, (size_t)32 * 32000 * 4, stream);

  prep_gather<<<3584, 128, 0, stream>>>(src, trg, emb, xbf, ebf, Zbf);

  // Gi precompute (input-side GRU gates, bih folded in)
  gemm_kernel<true><<<dim3(16, 12), 256, 0, stream>>>(xbf, 512, encf_Wih, 512, 0, encf_bih, Gif, 1536, 512, 2048, 0);
  gemm_kernel<true><<<dim3(16, 12), 256, 0, stream>>>(xbf, 512, encb_Wih, 512, 0, encb_bih, Gib, 1536, 512, 2048, 0);
  gemm_kernel<true><<<dim3(12, 12), 256, 0, stream>>>(ebf, 512, dec_Wih, 1536, 0, dec_bih, Gie, 1536, 512, 1536, 0);

  enc_kernel<<<128, 256, 0, stream>>>(Gif, Gib, encf_Whh, encb_Whh, encf_bhh, encb_bhh,
                                      fc_W, fc_b, hbuf, enc_out, sbufs, bar);

  // attention projections of enc_out (hoisted out of the decoder loop)
  gemm_kernel<false><<<dim3(16, 4), 256, 0, stream>>>(enc_out, 1024, attn_W, 1536, 512, nullptr, encproj, 512, 1024, 2048, 0);
  gemm_kernel<false><<<dim3(16, 12), 256, 0, stream>>>(enc_out, 1024, dec_Wih, 1536, 512, nullptr, EP2, 1536, 1024, 2048, 0);

  dec_kernel<<<128, 256, 0, stream>>>(attn_W, attn_v, dec_Whh, dec_bhh, encproj, EP2, Gie,
                                      enc_out, sbufs, sprojb, ghbuf, scoresb, Zbf, bar + 8);

  // output projection: preds = Z @ out_W^T + out_b, written to out rows 32..1535
  gemm_kernel<true><<<dim3(12, 250), 256, 0, stream>>>(Zbf, 2048, out_W, 2048, 0, out_b, out, 32000, 2048, 1504, 32);
}

// Round 2
// 2791.470 us; speedup vs baseline: 2.3626x; 2.3626x over previous
//
#include <hip/hip_runtime.h>
#include <stdint.h>
#include <stddef.h>

typedef __attribute__((ext_vector_type(8))) short short8;
typedef __attribute__((ext_vector_type(4))) float f32x4;

__device__ inline unsigned short f2bf(float f) {
  union { float f; uint32_t u; } v; v.f = f;
  uint32_t u = v.u;
  u += 0x7FFFu + ((u >> 16) & 1u);
  return (unsigned short)(u >> 16);
}
__device__ inline float bf2f(unsigned short h) {
  union { uint32_t u; float f; } v; v.u = ((uint32_t)h) << 16; return v.f;
}
__device__ inline short8 pack8(float4 a, float4 b) {
  short8 r;
  r[0] = (short)f2bf(a.x); r[1] = (short)f2bf(a.y);
  r[2] = (short)f2bf(a.z); r[3] = (short)f2bf(a.w);
  r[4] = (short)f2bf(b.x); r[5] = (short)f2bf(b.y);
  r[6] = (short)f2bf(b.z); r[7] = (short)f2bf(b.w);
  return r;
}
__device__ inline float tanh_fast(float x) {
  float xc = fminf(fmaxf(x, -9.f), 9.f);
  float e = __expf(2.f * xc);
  return (e - 1.f) * __builtin_amdgcn_rcpf(e + 1.f);
}
__device__ inline float sigm_fast(float x) {
  float xc = fminf(fmaxf(x, -30.f), 30.f);
  return __builtin_amdgcn_rcpf(1.f + __expf(-xc));
}
__device__ inline void arrive_cnt(int* c) {
  __threadfence();
  __hip_atomic_fetch_add(c, 1, __ATOMIC_RELEASE, __HIP_MEMORY_SCOPE_AGENT);
}
__device__ inline void wait_cnt(int* c, int tgt) {
  while (__hip_atomic_load(c, __ATOMIC_ACQUIRE, __HIP_MEMORY_SCOPE_AGENT) < tgt)
    __builtin_amdgcn_s_sleep(4);
}

// Gather + bf16-convert embeddings. rows 0..2047: xbf (src, row = s*32+b).
// rows 2048..3583: ebf (trg, row = t*32+b), also writes e-cols of Z.
__global__ __launch_bounds__(128) void prep_gather(
    const int* __restrict__ src, const int* __restrict__ trg,
    const float* __restrict__ emb,
    unsigned short* __restrict__ xbf, unsigned short* __restrict__ ebf,
    unsigned short* __restrict__ Zbf) {
  int r = blockIdx.x, tid = threadIdx.x;
  if (r < 2048) {
    int b = r & 31, s = r >> 5;
    int tok = src[b * 64 + s];
    const float* e = emb + (size_t)tok * 512;
    float4 v = *(const float4*)(e + tid * 4);
    unsigned short* dst = xbf + (size_t)r * 512 + tid * 4;
    dst[0] = f2bf(v.x); dst[1] = f2bf(v.y); dst[2] = f2bf(v.z); dst[3] = f2bf(v.w);
  } else {
    int rr = r - 2048;
    int t = rr >> 5, b = rr & 31;
    unsigned short* dst = ebf + (size_t)rr * 512 + tid * 4;
    if (t < 47) {
      int tok = trg[t * 32 + b];
      const float* e = emb + (size_t)tok * 512;
      float4 v = *(const float4*)(e + tid * 4);
      unsigned short q0 = f2bf(v.x), q1 = f2bf(v.y), q2 = f2bf(v.z), q3 = f2bf(v.w);
      dst[0] = q0; dst[1] = q1; dst[2] = q2; dst[3] = q3;
      unsigned short* zd = Zbf + (size_t)rr * 2048 + 1536 + tid * 4;
      zd[0] = q0; zd[1] = q1; zd[2] = q2; zd[3] = q3;
    } else {
      dst[0] = 0; dst[1] = 0; dst[2] = 0; dst[3] = 0;
    }
  }
}

__global__ __launch_bounds__(256) void cvt_f32_bf16(const float* __restrict__ src,
                                                    unsigned short* __restrict__ dst,
                                                    long long n4) {
  long long i = (long long)blockIdx.x * 256 + threadIdx.x;
  long long stride = (long long)gridDim.x * 256;
  for (; i < n4; i += stride) {
    float4 v = ((const float4*)src)[i];
    unsigned short* d = dst + i * 4;
    d[0] = f2bf(v.x); d[1] = f2bf(v.y); d[2] = f2bf(v.z); d[3] = f2bf(v.w);
  }
}

// C[m,n] = sum_k A[m,k]*B[n,k] (+bias[n]). 128x128 tile, BK=32, 4 waves.
template <bool ABF, bool BBF, bool WBF>
__global__ __launch_bounds__(256) void gemm_kernel(
    const void* __restrict__ Av, int lda,
    const void* __restrict__ Bv, int ldb, int bco,
    const float* __restrict__ bias,
    void* __restrict__ Cv, int ldc,
    int K, int Mvalid, int row_off) {
  __shared__ __align__(16) unsigned short As[128 * 32];
  __shared__ __align__(16) unsigned short Bs[128 * 32];
  const int tid = threadIdx.x;
  const int m0 = blockIdx.x * 128, n0 = blockIdx.y * 128;
  const int w = tid >> 6, lane = tid & 63;
  const int wm = w >> 1, wn = w & 1;
  const int fr = lane & 15, fq = lane >> 4;
  f32x4 acc[4][4];
#pragma unroll
  for (int mi = 0; mi < 4; ++mi)
#pragma unroll
    for (int ni = 0; ni < 4; ++ni) acc[mi][ni] = (f32x4){0.f, 0.f, 0.f, 0.f};
  for (int k0 = 0; k0 < K; k0 += 32) {
#pragma unroll
    for (int p = 0; p < 2; ++p) {
      int idx = p * 256 + tid;
      int row = idx >> 2, seg = idx & 3;
      if (ABF) {
        const unsigned short* Ab = (const unsigned short*)Av;
        *(short8*)(As + row * 32 + seg * 8) =
            *(const short8*)(Ab + (size_t)(m0 + row) * lda + k0 + seg * 8);
      } else {
        const float* Af = (const float*)Av;
        const float* ap = Af + (size_t)(m0 + row) * lda + k0 + seg * 8;
        *(short8*)(As + row * 32 + seg * 8) = pack8(*(const float4*)ap, *(const float4*)(ap + 4));
      }
      if (BBF) {
        const unsigned short* Bb = (const unsigned short*)Bv;
        *(short8*)(Bs + row * 32 + seg * 8) =
            *(const short8*)(Bb + (size_t)(n0 + row) * ldb + bco + k0 + seg * 8);
      } else {
        const float* Bf = (const float*)Bv;
        const float* bp = Bf + (size_t)(n0 + row) * ldb + bco + k0 + seg * 8;
        *(short8*)(Bs + row * 32 + seg * 8) = pack8(*(const float4*)bp, *(const float4*)(bp + 4));
      }
    }
    __syncthreads();
    short8 af[4], bfr[4];
#pragma unroll
    for (int mi = 0; mi < 4; ++mi)
      af[mi] = *(const short8*)(As + (wm * 64 + mi * 16 + fr) * 32 + fq * 8);
#pragma unroll
    for (int ni = 0; ni < 4; ++ni)
      bfr[ni] = *(const short8*)(Bs + (wn * 64 + ni * 16 + fr) * 32 + fq * 8);
#pragma unroll
    for (int mi = 0; mi < 4; ++mi)
#pragma unroll
      for (int ni = 0; ni < 4; ++ni)
        acc[mi][ni] = __builtin_amdgcn_mfma_f32_16x16x32_bf16(af[mi], bfr[ni], acc[mi][ni], 0, 0, 0);
    __syncthreads();
  }
#pragma unroll
  for (int mi = 0; mi < 4; ++mi)
#pragma unroll
    for (int ni = 0; ni < 4; ++ni) {
      int col = n0 + wn * 64 + ni * 16 + fr;
      float bv = bias ? bias[col] : 0.f;
#pragma unroll
      for (int j = 0; j < 4; ++j) {
        int rowm = m0 + wm * 64 + mi * 16 + fq * 4 + j;
        if (rowm < Mvalid) {
          float val = acc[mi][ni][j] + bv;
          if (WBF)
            ((unsigned short*)Cv)[(size_t)(rowm + row_off) * ldc + col] = f2bf(val);
          else
            ((float*)Cv)[(size_t)(rowm + row_off) * ldc + col] = val;
        }
      }
    }
}

// Bidirectional GRU encoder. 32 blocks: dir=blk>>4, 32-dim slice each.
// Whh slice resident in LDS (bf16); per-step producer/consumer counters per dir.
__global__ __launch_bounds__(512, 1) void enc_kernel(
    const float* __restrict__ Gif, const float* __restrict__ Gib,
    const float* __restrict__ whF, const float* __restrict__ whB,
    const float* __restrict__ bhhF, const float* __restrict__ bhhB,
    unsigned short* hbf,            // [dir][2][32][512]
    float* __restrict__ enc_out,    // [b][s][1024]
    unsigned short* __restrict__ ebo,
    float* __restrict__ hcat,       // [b][1024]
    int* cnt) {
  const int blk = blockIdx.x, tid = threadIdx.x;
  const int dir = blk >> 4, slice = blk & 15, D0 = slice * 32;
  const float* Whh = dir ? whB : whF;
  const float* Gi = dir ? Gib : Gif;
  const float* bhh = dir ? bhhB : bhhF;
  __shared__ __align__(16) unsigned short wlds[96 * 520];
  __shared__ __align__(16) unsigned short hlds[32 * 520];
  __shared__ __align__(16) float gl[96 * 33];
  for (int c = tid; c < 96 * 64; c += 512) {
    int lr = c >> 6, seg = c & 63;
    int gr = (lr >> 5) * 512 + D0 + (lr & 31);
    const float* wsrc = Whh + (size_t)gr * 512 + seg * 8;
    *(short8*)(wlds + lr * 520 + seg * 8) = pack8(*(const float4*)wsrc, *(const float4*)(wsrc + 4));
  }
  const int w = tid >> 6, lane = tid & 63, fr = lane & 15, fq = lane >> 4;
  unsigned short* hb0 = hbf + (size_t)dir * 2 * 32 * 512;
  float hprev[2] = {0.f, 0.f};
  for (int t = 0; t < 64; ++t) {
    const unsigned short* hsrc = hb0 + (t & 1) * 32 * 512;
    for (int c = tid; c < 32 * 64; c += 512) {
      int r = c >> 6, seg = c & 63;
      *(short8*)(hlds + r * 520 + seg * 8) = *(const short8*)(hsrc + r * 512 + seg * 8);
    }
    __syncthreads();
    if (w < 6) {
      f32x4 acc0 = {0.f, 0.f, 0.f, 0.f}, acc1 = {0.f, 0.f, 0.f, 0.f};
#pragma unroll
      for (int k0 = 0; k0 < 512; k0 += 32) {
        short8 bq = *(const short8*)(wlds + (w * 16 + fr) * 520 + k0 + fq * 8);
        short8 a0 = *(const short8*)(hlds + fr * 520 + k0 + fq * 8);
        short8 a1 = *(const short8*)(hlds + (16 + fr) * 520 + k0 + fq * 8);
        acc0 = __builtin_amdgcn_mfma_f32_16x16x32_bf16(a0, bq, acc0, 0, 0, 0);
        acc1 = __builtin_amdgcn_mfma_f32_16x16x32_bf16(a1, bq, acc1, 0, 0, 0);
      }
#pragma unroll
      for (int j = 0; j < 4; ++j) {
        gl[(w * 16 + fr) * 33 + fq * 4 + j] = acc0[j];
        gl[(w * 16 + fr) * 33 + 16 + fq * 4 + j] = acc1[j];
      }
    }
    __syncthreads();
    const int srow = dir ? 63 - t : t;
#pragma unroll
    for (int rep = 0; rep < 2; ++rep) {
      int idx = rep * 512 + tid, b = idx >> 5, dl = idx & 31, d = D0 + dl;
      float ar = gl[dl * 33 + b] + bhh[d];
      float az = gl[(32 + dl) * 33 + b] + bhh[512 + d];
      float an = gl[(64 + dl) * 33 + b] + bhh[1024 + d];
      const float* gi = Gi + ((size_t)srow * 32 + b) * 1536;
      float r = sigm_fast(gi[d] + ar);
      float z = sigm_fast(gi[512 + d] + az);
      float n = tanh_fast(gi[1024 + d] + r * an);
      float h2 = (1.f - z) * n + z * hprev[rep];
      hprev[rep] = h2;
      hb0[((t + 1) & 1) * 32 * 512 + b * 512 + d] = f2bf(h2);
      size_t eo = ((size_t)b * 64 + srow) * 1024 + (size_t)dir * 512 + d;
      enc_out[eo] = h2;
      ebo[eo] = f2bf(h2);
      if (t == 63) hcat[(size_t)b * 1024 + (size_t)dir * 512 + d] = h2;
    }
    __syncthreads();
    if (tid == 0) {
      arrive_cnt(&cnt[dir * 64 + t]);
      if (t < 63) wait_cnt(&cnt[dir * 64 + t], 16);
    }
    __syncthreads();
    __threadfence();
  }
}

__global__ __launch_bounds__(512) void tanh_s0(const float* __restrict__ s0raw,
                                               float* __restrict__ s0f,
                                               unsigned short* __restrict__ sbf) {
  int idx = blockIdx.x * 512 + threadIdx.x;
  float v = tanhf(s0raw[idx]);
  s0f[idx] = v;
  sbf[idx] = f2bf(v);
}

// Decoder: blocks 0..31 = G (sproj+gh MFMA, weights LDS-resident),
// blocks 32..63 = B (one per batch: scores/softmax/c/gic/gates, s in regs).
// Producer-consumer per-step counters, no grid barrier.
__global__ __launch_bounds__(512, 1) void dec_kernel(
    const float* __restrict__ attnW, const float* __restrict__ decWhh,
    const float* __restrict__ decBhh, const float* __restrict__ attnV,
    unsigned short* sbf, const float* __restrict__ s0f,
    const unsigned short* __restrict__ epf, const unsigned short* __restrict__ ebo,
    const unsigned short* __restrict__ EP2b, const float* __restrict__ Gie,
    float* gout, unsigned short* __restrict__ Zbf,
    int* gcnt, int* scnt) {
  __shared__ __align__(16) char smem[100352];
  const int blk = blockIdx.x, tid = threadIdx.x;
  if (blk < 32) {
    // ---- G role ----
    const int g = blk;
    unsigned short* wlds = (unsigned short*)smem;                     // 64*520
    unsigned short* slds = (unsigned short*)(smem + 64 * 520 * 2);    // 32*520
    float* wbias = (float*)(smem + 64 * 520 * 2 + 32 * 520 * 2);      // 64
    for (int c = tid; c < 64 * 64; c += 512) {
      int lr = c >> 6, seg = c & 63;
      int rc = g * 64 + lr;
      const float* srcp = rc < 512 ? attnW + (size_t)rc * 1536 + seg * 8
                                   : decWhh + (size_t)(rc - 512) * 512 + seg * 8;
      *(short8*)(wlds + lr * 520 + seg * 8) = pack8(*(const float4*)srcp, *(const float4*)(srcp + 4));
    }
    if (tid < 64) {
      int rc = g * 64 + tid;
      wbias[tid] = rc < 512 ? 0.f : decBhh[rc - 512];
    }
    const int w = tid >> 6, lane = tid & 63, fr = lane & 15, fq = lane >> 4;
    for (int t = 0; t < 47; ++t) {
      if (tid == 0 && t > 0) wait_cnt(&scnt[t - 1], 32);
      __syncthreads();
      __threadfence();
      for (int c = tid; c < 32 * 64; c += 512) {
        int r = c >> 6, seg = c & 63;
        *(short8*)(slds + r * 520 + seg * 8) = *(const short8*)(sbf + r * 512 + seg * 8);
      }
      __syncthreads();
      if (w < 4) {
        f32x4 acc0 = {0.f, 0.f, 0.f, 0.f}, acc1 = {0.f, 0.f, 0.f, 0.f};
#pragma unroll
        for (int k0 = 0; k0 < 512; k0 += 32) {
          short8 bq = *(const short8*)(wlds + (w * 16 + fr) * 520 + k0 + fq * 8);
          short8 a0 = *(const short8*)(slds + fr * 520 + k0 + fq * 8);
          short8 a1 = *(const short8*)(slds + (16 + fr) * 520 + k0 + fq * 8);
          acc0 = __builtin_amdgcn_mfma_f32_16x16x32_bf16(a0, bq, acc0, 0, 0, 0);
          acc1 = __builtin_amdgcn_mfma_f32_16x16x32_bf16(a1, bq, acc1, 0, 0, 0);
        }
        int n = g * 64 + w * 16 + fr;
        float bv = wbias[w * 16 + fr];
#pragma unroll
        for (int j = 0; j < 4; ++j) {
          gout[(size_t)(fq * 4 + j) * 2048 + n] = acc0[j] + bv;
          gout[(size_t)(16 + fq * 4 + j) * 2048 + n] = acc1[j] + bv;
        }
      }
      __syncthreads();
      if (tid == 0) arrive_cnt(&gcnt[t]);
    }
  } else {
    // ---- B role ----
    const int b = blk - 32;
    float* raw = (float*)smem;
    float* aaw = raw + 64;
    float sreg = s0f[b * 512 + tid];
    const int s_i = tid >> 3, l8 = tid & 7;
    for (int t = 0; t < 47; ++t) {
      if (tid == 0) wait_cnt(&gcnt[t], 32);
      __syncthreads();
      __threadfence();
      // scores: energy[b,s] = v . tanh(sproj + encproj)
      {
        float part = 0.f;
        const float* gp = gout + (size_t)b * 2048 + l8 * 64;
        const unsigned short* ep = epf + ((size_t)b * 64 + s_i) * 512 + l8 * 64;
        const float* vv = attnV + l8 * 64;
#pragma unroll
        for (int jc = 0; jc < 8; ++jc) {
          short8 e8 = *(const short8*)(ep + jc * 8);
          float4 g0 = *(const float4*)(gp + jc * 8);
          float4 g1 = *(const float4*)(gp + jc * 8 + 4);
          float4 v0 = *(const float4*)(vv + jc * 8);
          float4 v1 = *(const float4*)(vv + jc * 8 + 4);
          part += tanh_fast(g0.x + bf2f((unsigned short)e8[0])) * v0.x;
          part += tanh_fast(g0.y + bf2f((unsigned short)e8[1])) * v0.y;
          part += tanh_fast(g0.z + bf2f((unsigned short)e8[2])) * v0.z;
          part += tanh_fast(g0.w + bf2f((unsigned short)e8[3])) * v0.w;
          part += tanh_fast(g1.x + bf2f((unsigned short)e8[4])) * v1.x;
          part += tanh_fast(g1.y + bf2f((unsigned short)e8[5])) * v1.y;
          part += tanh_fast(g1.z + bf2f((unsigned short)e8[6])) * v1.z;
          part += tanh_fast(g1.w + bf2f((unsigned short)e8[7])) * v1.w;
        }
        part += __shfl_xor(part, 1);
        part += __shfl_xor(part, 2);
        part += __shfl_xor(part, 4);
        if (l8 == 0) raw[s_i] = part;
      }
      __syncthreads();
      if (tid < 64) {
        float x = raw[tid];
        float m = x;
#pragma unroll
        for (int k = 1; k < 64; k <<= 1) m = fmaxf(m, __shfl_xor(m, k));
        float e = __expf(x - m);
        float s = e;
#pragma unroll
        for (int k = 1; k < 64; k <<= 1) s += __shfl_xor(s, k);
        aaw[tid] = e * __builtin_amdgcn_rcpf(s);
      }
      __syncthreads();
      // c (2 cols) + gic (3 rows) per thread
      float c0 = 0.f, c1 = 0.f, g0a = 0.f, g1a = 0.f, g2a = 0.f;
      const unsigned short* eb = ebo + (size_t)b * 64 * 1024 + tid;
      const unsigned short* e2 = EP2b + (size_t)b * 64 * 1536 + tid;
#pragma unroll 8
      for (int s2 = 0; s2 < 64; ++s2) {
        float a = aaw[s2];
        c0 += a * bf2f(eb[(size_t)s2 * 1024]);
        c1 += a * bf2f(eb[(size_t)s2 * 1024 + 512]);
        g0a += a * bf2f(e2[(size_t)s2 * 1536]);
        g1a += a * bf2f(e2[(size_t)s2 * 1536 + 512]);
        g2a += a * bf2f(e2[(size_t)s2 * 1536 + 1024]);
      }
      size_t zrow = ((size_t)t * 32 + b) * 2048;
      Zbf[zrow + 512 + tid] = f2bf(c0);
      Zbf[zrow + 1024 + tid] = f2bf(c1);
      const float* gie = Gie + ((size_t)t * 32 + b) * 1536;
      const float* gh = gout + (size_t)b * 2048;
      float rr = sigm_fast(gie[tid] + g0a + gh[512 + tid]);
      float zz = sigm_fast(gie[512 + tid] + g1a + gh[1024 + tid]);
      float nn = tanh_fast(gie[1024 + tid] + g2a + rr * gh[1536 + tid]);
      float s2v = (1.f - zz) * nn + zz * sreg;
      sreg = s2v;
      sbf[b * 512 + tid] = f2bf(s2v);
      Zbf[zrow + tid] = f2bf(s2v);
      __syncthreads();
      if (tid == 0) arrive_cnt(&scnt[t]);
    }
  }
}

extern "C" void kernel_launch(void* const* d_in, const int* in_sizes, int n_in,
                              void* d_out, int out_size, void* d_ws, size_t ws_size,
                              hipStream_t stream) {
  (void)in_sizes; (void)n_in; (void)out_size;
  const int* src = (const int*)d_in[0];
  const int* trg = (const int*)d_in[1];
  const float* emb = (const float*)d_in[2];
  const float* encf_Wih = (const float*)d_in[3];
  const float* encf_Whh = (const float*)d_in[4];
  const float* encf_bih = (const float*)d_in[5];
  const float* encf_bhh = (const float*)d_in[6];
  const float* encb_Wih = (const float*)d_in[7];
  const float* encb_Whh = (const float*)d_in[8];
  const float* encb_bih = (const float*)d_in[9];
  const float* encb_bhh = (const float*)d_in[10];
  const float* fc_W = (const float*)d_in[11];
  const float* fc_b = (const float*)d_in[12];
  const float* attn_W = (const float*)d_in[13];
  const float* attn_v = (const float*)d_in[14];
  const float* dec_Wih = (const float*)d_in[15];
  const float* dec_Whh = (const float*)d_in[16];
  const float* dec_bih = (const float*)d_in[17];
  const float* dec_bhh = (const float*)d_in[18];
  const float* out_W = (const float*)d_in[19];
  const float* out_b = (const float*)d_in[20];
  float* out = (float*)d_out;

  char* p = (char*)d_ws;
  size_t off = 0;
  auto alloc = [&](size_t bytes) {
    void* r = p + off;
    off = (off + bytes + 255) & ~(size_t)255;
    return r;
  };
  int* cnt = (int*)alloc(1024);  // gcnt[48] | scnt[48] | cnt_h[128]
  int* gcnt = cnt;
  int* scnt = cnt + 48;
  int* hcnt = cnt + 96;
  unsigned short* xbf = (unsigned short*)alloc((size_t)2048 * 512 * 2);
  unsigned short* ebf = (unsigned short*)alloc((size_t)1536 * 512 * 2);
  unsigned short* Zbf = (unsigned short*)alloc((size_t)1536 * 2048 * 2);
  float* Gif = (float*)alloc((size_t)2048 * 1536 * 4);
  float* Gib = (float*)alloc((size_t)2048 * 1536 * 4);
  float* Gie = (float*)alloc((size_t)1536 * 1536 * 4);
  float* enc_out = (float*)alloc((size_t)2048 * 1024 * 4);
  unsigned short* ebo = (unsigned short*)alloc((size_t)2048 * 1024 * 2);
  unsigned short* epf = (unsigned short*)alloc((size_t)2048 * 512 * 2);
  unsigned short* EP2b = (unsigned short*)alloc((size_t)2048 * 1536 * 2);
  unsigned short* hbf = (unsigned short*)alloc((size_t)2 * 2 * 32 * 512 * 2);
  float* hcat = (float*)alloc((size_t)128 * 1024 * 4);
  float* s0raw = (float*)alloc((size_t)32 * 512 * 4);
  float* s0f = (float*)alloc((size_t)32 * 512 * 4);
  unsigned short* sbf = (unsigned short*)alloc((size_t)32 * 512 * 2);
  float* gout = (float*)alloc((size_t)32 * 2048 * 4);
  size_t base_end = off;
  unsigned short* outWbf = (unsigned short*)alloc((size_t)32000 * 2048 * 2);
  const bool bigB = (off <= ws_size);
  (void)base_end;

  hipMemsetAsync(cnt, 0, 1024, stream);
  hipMemsetAsync(hbf, 0, (size_t)2 * 2 * 32 * 512 * 2, stream);
  hipMemsetAsync(d_out, 0, (size_t)32 * 32000 * 4, stream);

  prep_gather<<<3584, 128, 0, stream>>>(src, trg, emb, xbf, ebf, Zbf);
  if (bigB)
    cvt_f32_bf16<<<4096, 256, 0, stream>>>(out_W, outWbf, (long long)32000 * 2048 / 4);

  gemm_kernel<true, false, false><<<dim3(16, 12), 256, 0, stream>>>(
      xbf, 512, encf_Wih, 512, 0, encf_bih, Gif, 1536, 512, 2048, 0);
  gemm_kernel<true, false, false><<<dim3(16, 12), 256, 0, stream>>>(
      xbf, 512, encb_Wih, 512, 0, encb_bih, Gib, 1536, 512, 2048, 0);
  gemm_kernel<true, false, false><<<dim3(12, 12), 256, 0, stream>>>(
      ebf, 512, dec_Wih, 1536, 0, dec_bih, Gie, 1536, 512, 1536, 0);

  enc_kernel<<<32, 512, 0, stream>>>(Gif, Gib, encf_Whh, encb_Whh, encf_bhh, encb_bhh,
                                     hbf, enc_out, ebo, hcat, hcnt);

  gemm_kernel<false, false, false><<<dim3(1, 4), 256, 0, stream>>>(
      hcat, 1024, fc_W, 1024, 0, fc_b, s0raw, 512, 1024, 32, 0);
  tanh_s0<<<32, 512, 0, stream>>>(s0raw, s0f, sbf);

  gemm_kernel<false, false, true><<<dim3(16, 4), 256, 0, stream>>>(
      enc_out, 1024, attn_W, 1536, 512, nullptr, epf, 512, 1024, 2048, 0);
  gemm_kernel<false, false, true><<<dim3(16, 12), 256, 0, stream>>>(
      enc_out, 1024, dec_Wih, 1536, 512, nullptr, EP2b, 1536, 1024, 2048, 0);

  dec_kernel<<<64, 512, 0, stream>>>(attn_W, dec_Whh, dec_bhh, attn_v, sbf, s0f,
                                     epf, ebo, EP2b, Gie, gout, Zbf, gcnt, scnt);

  if (bigB)
    gemm_kernel<true, true, false><<<dim3(12, 250), 256, 0, stream>>>(
        Zbf, 2048, outWbf, 2048, 0, out_b, out, 32000, 2048, 1504, 32);
  else
    gemm_kernel<true, false, false><<<dim3(12, 250), 256, 0, stream>>>(
        Zbf, 2048, out_W, 2048, 0, out_b, out, 32000, 2048, 1504, 32);
}